// Round 2
// baseline (3260.383 us; speedup 1.0000x reference)
//
#include <hip/hip_runtime.h>
#include <cstdint>

// LSTM persistent kernel for MI355X (gfx950), round 4 (= R3 resubmit, hardened).
// B=256, T=1024, I=128, H=256, O=128. All inputs/outputs fp32.
//
// Grid: 256 WGs = 16 batch-groups x 16 column-tiles; one WG/CU (forced by LDS).
// Weights in registers as bf16 hi/lo MFMA B-fragments (bf16x3 split products).
//
// R3 design: SELF-VALIDATING h exchange. The per-step flag protocol (store h ->
// vmcnt(0) drain -> flag store -> consumer flag poll -> consumer h load) cost
// two serialized L3 round trips plus a store-ack drain. Now each published h
// word carries a 2-bit step tag (t&3) in the low 2 mantissa bits of the lo
// bf16 correction (error ~2^-15 relative - negligible; hi product untouched).
// Consumers poll the DATA directly and accept when all words show the expected
// tag: one L3 round trip total, and the producer's store is fire-and-forget
// (post-store barrier is raw lgkmcnt-only, no vmcnt(0) store-ack stall).
// Stale data (t-2, same parity buffer) always differs in tag bit 1.
//
// R4 hardening (R3 never ran - container failure):
//  - lgkm_barrier: memory-clobber asm on BOTH sides of s_barrier (s_barrier is
//    not an IR memory op; LDS accesses could otherwise be moved across it).
//  - s_sleep(1) restored on poll retry paths (R2's proven spin shape).
//  - init tags made unsatisfiable: parity0 init = 0x00010000 (tag 1; parity-0
//    polls only accept {2,0}), parity1 init = 0 (tag 0; parity-1 polls accept
//    {1,3}). No init value can ever satisfy any poll -> no reliance on
//    store-drain timing for the tag-0 cases. Workspace poison 0xAAAAAAAA
//    (tag 2) is still overwritten by the init, which is drained to L3 by the
//    first __syncthreads (vmcnt(0)) before any h is published; a consumer's
//    first parity-0 poll (t=2) is causally after the producer's h_1 publish,
//    hence after the init reached the coherence point.

#define T_    1024
#define I_    128
#define H_    256

typedef short s8v __attribute__((ext_vector_type(8)));
typedef float f4v __attribute__((ext_vector_type(4)));
typedef unsigned short u16;
typedef unsigned int   u32;
typedef unsigned long long u64;

__device__ __forceinline__ u16 f2bf(float f) {
  union { float f; u32 u; } v; v.f = f;
  u32 r = v.u + 0x7FFFu + ((v.u >> 16) & 1u);
  return (u16)(r >> 16);
}
__device__ __forceinline__ float bf2f(u16 h) {
  union { u32 u; float f; } v; v.u = ((u32)h) << 16;
  return v.f;
}
__device__ __forceinline__ float sig_(float x)  { return 1.0f / (1.0f + __expf(-x)); }
__device__ __forceinline__ float tanh_(float x) { return 2.0f / (1.0f + __expf(-2.0f * x)) - 1.0f; }

// unpack 4x u64 (8 packed elements: lo16=hi-bf16, hi16=lo-bf16) -> hi/lo s8v
__device__ __forceinline__ void unpack8(const u64 w[4], s8v& hi, s8v& lo) {
  #pragma unroll
  for (int j = 0; j < 4; j++) {
    u32 a = (u32)w[j], b = (u32)(w[j] >> 32);
    hi[2*j]   = (short)(u16)a;        lo[2*j]   = (short)(u16)(a >> 16);
    hi[2*j+1] = (short)(u16)b;        lo[2*j+1] = (short)(u16)(b >> 16);
  }
}

// both 16-bit halves of both packed values carry tag in lo-mantissa bits 0-1
// (u32 bits 16-17; u64 bits 16-17 and 48-49)
__device__ __forceinline__ bool tagok(u64 w, u32 tag) {
  return ((((u32)(w >> 16)) & 3u) == tag) & ((((u32)(w >> 48)) & 3u) == tag);
}

// barrier that waits LDS only (no vmcnt(0) drain of in-flight global stores).
// Memory-clobber asm on both sides: s_barrier is not an IR-level memory op,
// so without the clobbers the compiler may move LDS accesses across it.
__device__ __forceinline__ void lgkm_barrier() {
  asm volatile("s_waitcnt lgkmcnt(0)" ::: "memory");
  __builtin_amdgcn_sched_barrier(0);
  __builtin_amdgcn_s_barrier();
  __builtin_amdgcn_sched_barrier(0);
  asm volatile("" ::: "memory");
}

__global__ __launch_bounds__(256, 1) void lstm_persist(
    const float* __restrict__ x, const float* __restrict__ Wih,
    const float* __restrict__ Whh, const float* __restrict__ bih,
    const float* __restrict__ bhh, const float* __restrict__ Wout,
    const float* __restrict__ bout, float* __restrict__ out,
    u32* __restrict__ flags, u32* __restrict__ hbuf)
{
  (void)flags;   // flag protocol removed; data self-validates via tags
  const int bid  = blockIdx.x;
  // XCD co-location heuristic (perf-only): group members share bid&7.
  const int xcd  = bid & 7;
  const int slot = bid >> 3;
  const int ct   = slot & 15;                 // column tile (0..15)
  const int g    = ((slot >> 4) << 3) | xcd;  // batch group (0..15)
  const int tid  = threadIdx.x;
  const int wave = tid >> 6;
  const int lane = tid & 63;
  const int lm   = lane & 15;   // MFMA m (A) / n (B) index
  const int lq   = lane >> 4;   // MFMA quad

  __shared__ u16   Wlds[2][64][392];        // setup W staging; reused for W_out
  __shared__ u16   xlds[2][2][16][136];     // [parity][hi/lo][m][k(128)+pad]
  __shared__ float partial[4][4][16][20];   // [wave][gate][m][hc+pad]

  // cell-update thread mapping: one thread per (batch m, h-col)
  const int cm  = tid >> 4;
  const int chc = tid & 15;

  const size_t hpar   = (size_t)16 * 16 * 256;  // parity stride (u32 elems)
  const size_t hgbase = (size_t)g * 16 * 256;   // group base within parity

  // ---- init this WG's h slice in BOTH parities with unsatisfiable tags.
  // parity0 polls accept tags {2,0} -> init tag 1 (0x00010000: lo-bf16 is a
  // tiny denormal, hi=0; value can never be consumed anyway).
  // parity1 polls accept tags {1,3} -> init tag 0 (zero).
  // Drained to L3 by the first __syncthreads (vmcnt(0)) below.
  {
    u32* hz = hbuf + hgbase + (size_t)cm * 256 + ct * 16 + chc;
    __hip_atomic_store(hz,        0x00010000u, __ATOMIC_RELAXED, __HIP_MEMORY_SCOPE_AGENT);
    __hip_atomic_store(hz + hpar, 0u,          __ATOMIC_RELAXED, __HIP_MEMORY_SCOPE_AGENT);
  }

  // ---- stage W slice (concat Wih rows 0..127, Whh rows 128..383) col-major ----
  for (int it = tid; it < 384 * 64; it += 256) {
    int k = it >> 6;
    int c = it & 63;                              // gate = c>>4, n = c&15
    int gcol = (c >> 4) * 256 + ct * 16 + (c & 15);
    float w = (k < 128) ? Wih[k * 1024 + gcol] : Whh[(k - 128) * 1024 + gcol];
    u16 hi = f2bf(w);
    Wlds[0][c][k] = hi;
    Wlds[1][c][k] = f2bf(w - bf2f(hi));
  }
  __syncthreads();

  // ---- per-wave W fragments in registers: wave owns k-tiles {w, w+4, w+8} ----
  // B-frag layout (16x16x32): lane holds B[k = lq*8+j][n = lm], j=0..7.
  s8v wfrag[3][4][2];
  #pragma unroll
  for (int ki = 0; ki < 3; ki++) {
    const int kt = wave + 4 * ki;
    #pragma unroll
    for (int gg = 0; gg < 4; gg++) {
      #pragma unroll
      for (int p = 0; p < 2; p++)
        wfrag[ki][gg][p] = *(const s8v*)&Wlds[p][gg * 16 + lm][kt * 32 + lq * 8];
    }
  }
  __syncthreads();

  float biasv[4];
  #pragma unroll
  for (int gg = 0; gg < 4; gg++) {
    int col = gg * 256 + ct * 16 + chc;
    biasv[gg] = bih[col] + bhh[col];
  }
  float cstate = 0.0f;

  // x prefetch mapping: thread loads x[g*16+xr][t][xc0..xc0+7]
  const int xr  = tid >> 4;
  const int xc0 = (tid & 15) * 8;
  const float* xbase = x + (size_t)(g * 16 + xr) * (T_ * I_) + xc0;

  auto xstore = [&](int par, float4 a, float4 b) {
    float v[8] = {a.x, a.y, a.z, a.w, b.x, b.y, b.z, b.w};
    union { u16 u[8]; s8v s; } hi, lo;
    #pragma unroll
    for (int j = 0; j < 8; j++) {
      u16 h = f2bf(v[j]);
      hi.u[j] = h;
      lo.u[j] = f2bf(v[j] - bf2f(h));
    }
    *(s8v*)&xlds[par][0][xr][xc0] = hi.s;
    *(s8v*)&xlds[par][1][xr][xc0] = lo.s;
  };

  { // x_0 into parity 0
    float4 a = *(const float4*)(xbase + 0);
    float4 b = *(const float4*)(xbase + 4);
    xstore(0, a, b);
  }
  __syncthreads();

  for (int t = 0; t < T_; t++) {
    const int par = t & 1;
    const int pn  = (t + 1) & 1;

    // prefetch x_{t+1} (clamped; read-only data)
    const int tn = (t + 1 < T_) ? (t + 1) : t;
    float4 xa = *(const float4*)(xbase + (size_t)tn * I_);
    float4 xb = *(const float4*)(xbase + (size_t)tn * I_ + 4);

    f4v acc[4];
    #pragma unroll
    for (int gg = 0; gg < 4; gg++)
      #pragma unroll
      for (int r = 0; r < 4; r++) acc[gg][r] = 0.0f;

    // x-part MFMA (k-tile = wave), independent of peers -> runs before poll.
    {
      s8v axh = *(const s8v*)&xlds[par][0][lm][wave * 32 + lq * 8];
      s8v axl = *(const s8v*)&xlds[par][1][lm][wave * 32 + lq * 8];
      #pragma unroll
      for (int gg = 0; gg < 4; gg++) {
        acc[gg] = __builtin_amdgcn_mfma_f32_16x16x32_bf16(axh, wfrag[0][gg][0], acc[gg], 0, 0, 0);
        acc[gg] = __builtin_amdgcn_mfma_f32_16x16x32_bf16(axl, wfrag[0][gg][0], acc[gg], 0, 0, 0);
        acc[gg] = __builtin_amdgcn_mfma_f32_16x16x32_bf16(axh, wfrag[0][gg][1], acc[gg], 0, 0, 0);
      }
    }

    if (t > 0) {
      // poll the h data itself until every word carries tag t&3.
      // One L3 round trip: the validating load IS the data load. Stale data
      // (t-2) differs in tag bit 1; init tags never match any poll.
      // Causality (publish gated on all peers' previous publishes, and each
      // WG's publish is after its mid-barrier, hence after ALL its threads'
      // polls) prevents overwrite of h_t by h_{t+2} before consumption.
      const u32 tag = (u32)(t & 3);
      const u32* hb0 = hbuf + (size_t)par * hpar + hgbase;
      const u64* hp1 = (const u64*)(hb0 + (size_t)lm * 256 + (wave * 32 + lq * 8));
      const u64* hp2 = (const u64*)(hb0 + (size_t)lm * 256 + (wave * 32 + 128 + lq * 8));
      u64 w1[4], w2[4];
      while (true) {
        #pragma unroll
        for (int j = 0; j < 4; j++) {
          w1[j] = __hip_atomic_load(hp1 + j, __ATOMIC_RELAXED, __HIP_MEMORY_SCOPE_AGENT);
          w2[j] = __hip_atomic_load(hp2 + j, __ATOMIC_RELAXED, __HIP_MEMORY_SCOPE_AGENT);
        }
        bool ok = true;
        #pragma unroll
        for (int j = 0; j < 4; j++) {
          ok &= tagok(w1[j], tag);
          ok &= tagok(w2[j], tag);
        }
        if (__all(ok)) break;
        __builtin_amdgcn_s_sleep(1);
      }
      {
        s8v ahh, ahl;
        unpack8(w1, ahh, ahl);
        #pragma unroll
        for (int gg = 0; gg < 4; gg++) {
          acc[gg] = __builtin_amdgcn_mfma_f32_16x16x32_bf16(ahh, wfrag[1][gg][0], acc[gg], 0, 0, 0);
          acc[gg] = __builtin_amdgcn_mfma_f32_16x16x32_bf16(ahl, wfrag[1][gg][0], acc[gg], 0, 0, 0);
          acc[gg] = __builtin_amdgcn_mfma_f32_16x16x32_bf16(ahh, wfrag[1][gg][1], acc[gg], 0, 0, 0);
        }
        unpack8(w2, ahh, ahl);
        #pragma unroll
        for (int gg = 0; gg < 4; gg++) {
          acc[gg] = __builtin_amdgcn_mfma_f32_16x16x32_bf16(ahh, wfrag[2][gg][0], acc[gg], 0, 0, 0);
          acc[gg] = __builtin_amdgcn_mfma_f32_16x16x32_bf16(ahl, wfrag[2][gg][0], acc[gg], 0, 0, 0);
          acc[gg] = __builtin_amdgcn_mfma_f32_16x16x32_bf16(ahh, wfrag[2][gg][1], acc[gg], 0, 0, 0);
        }
      }
    }

    // write per-wave partial gates (C layout: col=lm, row=lq*4+r)
    #pragma unroll
    for (int gg = 0; gg < 4; gg++)
      #pragma unroll
      for (int r = 0; r < 4; r++)
        partial[wave][gg][lq * 4 + r][lm] = acc[gg][r];

    // convert x_{t+1} into the other parity's LDS planes (safe anywhere this
    // iteration: last reader of xlds[pn] was iter t-1, ordered by its barriers)
    xstore(pn, xa, xb);

    __syncthreads();   // partials + xlds[pn] visible; x prefetch long since done

    // cell update: thread (cm, chc)
    float ga = biasv[0], gb = biasv[1], gc = biasv[2], gd = biasv[3];
    #pragma unroll
    for (int w = 0; w < 4; w++) {
      ga += partial[w][0][cm][chc];
      gb += partial[w][1][cm][chc];
      gc += partial[w][2][cm][chc];
      gd += partial[w][3][cm][chc];
    }
    float i_t = sig_(ga), f_t = sig_(gb), g_t = tanh_(gc), o_t = sig_(gd);
    cstate = f_t * cstate + i_t * g_t;
    float h = o_t * tanh_(cstate);

    // publish h_{t+1}: packed (lo<<16)|hi with tag (t+1)&3 in lo mantissa
    // bits 0-1 (error ~2^-15 relative). Fire-and-forget: no drain, no flag.
    u16 hhi = f2bf(h);
    u16 hlo = f2bf(h - bf2f(hhi));
    u32 pk  = ((u32)((hlo & 0xFFFCu) | (u32)((t + 1) & 3)) << 16) | (u32)hhi;
    u32* hw = hbuf + (size_t)pn * hpar + hgbase + (size_t)cm * 256 + ct * 16 + chc;
    __hip_atomic_store(hw, pk, __ATOMIC_RELAXED, __HIP_MEMORY_SCOPE_AGENT);

    // raw lgkm-only barrier: guards partial-read vs next-iter partial-write
    // and xlds ordering. Deliberately does NOT wait vmcnt (h store in flight).
    lgkm_barrier();
  }

  // ---- output projection: out = h_T @ W_out + b_out ----
  // wait for h_T via data poll (tag 1024&3 == 0) and keep the words.
  // Stale value at these addresses is h_1022 (tag 2) or older even-tagged h;
  // all h_{4k} (tag 0) predecessors were overwritten at L3 in coherence order
  // before h_1022 (same producer thread, same address, program order), and
  // h_1022 visibility precedes this WG's own step-1022 completion.
  u64 wf0[4], wf1[4];
  {
    const u32* hb0 = hbuf + hgbase;   // h_T lives at parity (1024 & 1) == 0
    const u64* hpa = (const u64*)(hb0 + (size_t)lm * 256 + ((wave * 2 + 0) * 32 + lq * 8));
    const u64* hpb = (const u64*)(hb0 + (size_t)lm * 256 + ((wave * 2 + 1) * 32 + lq * 8));
    while (true) {
      #pragma unroll
      for (int j = 0; j < 4; j++) {
        wf0[j] = __hip_atomic_load(hpa + j, __ATOMIC_RELAXED, __HIP_MEMORY_SCOPE_AGENT);
        wf1[j] = __hip_atomic_load(hpb + j, __ATOMIC_RELAXED, __HIP_MEMORY_SCOPE_AGENT);
      }
      bool ok = true;
      #pragma unroll
      for (int j = 0; j < 4; j++) {
        ok &= tagok(wf0[j], 0u);
        ok &= tagok(wf1[j], 0u);
      }
      if (__all(ok)) break;
      __builtin_amdgcn_s_sleep(1);
    }
  }
  __syncthreads();
  // stage W_out cols [ct*8, ct*8+8) into Wlds[p][n][k], zero-pad n in [8,16)
  for (int it = tid; it < 16 * 256; it += 256) {
    int n = it >> 8;
    int k = it & 255;
    float w = (n < 8) ? Wout[k * 128 + ct * 8 + n] : 0.0f;
    u16 hi = f2bf(w);
    Wlds[0][n][k] = hi;
    Wlds[1][n][k] = f2bf(w - bf2f(hi));
  }
  __syncthreads();

  f4v oacc;
  #pragma unroll
  for (int r = 0; r < 4; r++) oacc[r] = 0.0f;
  #pragma unroll
  for (int ki = 0; ki < 2; ki++) {
    const int hk = (wave * 2 + ki) * 32 + lq * 8;
    s8v ahh, ahl;
    unpack8(ki == 0 ? wf0 : wf1, ahh, ahl);
    s8v bh  = *(const s8v*)&Wlds[0][lm][hk];
    s8v bl  = *(const s8v*)&Wlds[1][lm][hk];
    oacc = __builtin_amdgcn_mfma_f32_16x16x32_bf16(ahh, bh, oacc, 0, 0, 0);
    oacc = __builtin_amdgcn_mfma_f32_16x16x32_bf16(ahl, bh, oacc, 0, 0, 0);
    oacc = __builtin_amdgcn_mfma_f32_16x16x32_bf16(ahh, bl, oacc, 0, 0, 0);
  }
  #pragma unroll
  for (int r = 0; r < 4; r++) partial[wave][0][lq * 4 + r][lm] = oacc[r];
  __syncthreads();

  if (tid < 128) {
    int m  = tid >> 3;
    int oc = tid & 7;
    float v = bout[ct * 8 + oc];
    #pragma unroll
    for (int w = 0; w < 4; w++) v += partial[w][0][m][oc];
    out[(size_t)(g * 16 + m) * 128 + ct * 8 + oc] = v;
  }
}

extern "C" void kernel_launch(void* const* d_in, const int* in_sizes, int n_in,
                              void* d_out, int out_size, void* d_ws, size_t ws_size,
                              hipStream_t stream) {
  const float* x    = (const float*)d_in[0];
  const float* Wih  = (const float*)d_in[1];
  const float* Whh  = (const float*)d_in[2];
  const float* bih  = (const float*)d_in[3];
  const float* bhh  = (const float*)d_in[4];
  const float* Wout = (const float*)d_in[5];
  const float* bout = (const float*)d_in[6];
  float* out = (float*)d_out;

  char* ws = (char*)d_ws;
  u32* flags = (u32*)ws;               // unused (kept for ABI stability)
  u32* hbuf  = (u32*)(ws + 4096);      // 2 parities * 16 g * 16 * 256 * 4 B = 512 KB
  hipLaunchKernelGGL(lstm_persist, dim3(256), dim3(256), 0, stream,
                     x, Wih, Whh, bih, bhh, Wout, bout, out, flags, hbuf);
}

// Round 4
// 3195.384 us; speedup vs baseline: 1.0203x; 1.0203x over previous
//
#include <hip/hip_runtime.h>
#include <cstdint>

// LSTM persistent kernel for MI355X (gfx950), round 6.
// B=256, T=1024, I=128, H=256, O=128. All inputs/outputs fp32.
//
// Grid: 256 WGs = 16 batch-groups x 16 column-tiles; one WG/CU (forced by LDS).
// Weights in registers as bf16 hi/lo MFMA B-fragments (bf16x3 split products).
// Self-validating h exchange (R4): each published u32 carries a 2-bit step tag
// in the lo-correction mantissa; consumers poll the data itself.
//
// R6 = hang-proofed hybrid of R4 (agent/L3 exchange, proven) and R5 (XCD-local
// L2 exchange, upside unproven):
//  - h publishes are ALWAYS write-through to the coherence point (sc0 sc1 =
//    agent-store semantics). Data is never dirty-in-L2, so no load flavor can
//    read around it; if write-through updates/invalidates the XCD-shared L2
//    en route, co-XCD consumers can detect it at ~L2 RTT.
//  - poll loop alternates: one speculative sc0 attempt (L1-bypass, served by
//    the XCD-shared L2; stale results just fail the tag check) then one
//    guaranteed agent-scope atomic attempt (exact R4 path, guaranteed
//    progress). Worst case = R4 poll + ~200cy/iteration; best case = L2-RTT
//    detection. NO unbounded-stale spin exists in any mode/mapping.
//  - XCC handshake (HW_REG_XCC_ID) only gates the speculative attempt on/off;
//    correctness does not depend on it.

#define T_    1024
#define I_    128
#define H_    256

typedef short s8v __attribute__((ext_vector_type(8)));
typedef float f4v __attribute__((ext_vector_type(4)));
typedef unsigned short u16;
typedef unsigned int   u32;
typedef unsigned long long u64;

__device__ __forceinline__ u16 f2bf(float f) {
  union { float f; u32 u; } v; v.f = f;
  u32 r = v.u + 0x7FFFu + ((v.u >> 16) & 1u);
  return (u16)(r >> 16);
}
__device__ __forceinline__ float bf2f(u16 h) {
  union { u32 u; float f; } v; v.u = ((u32)h) << 16;
  return v.f;
}
__device__ __forceinline__ float sig_(float x)  { return 1.0f / (1.0f + __expf(-x)); }
__device__ __forceinline__ float tanh_(float x) { return 2.0f / (1.0f + __expf(-2.0f * x)) - 1.0f; }

// unpack 4x u64 (8 packed elements: lo16=hi-bf16, hi16=lo-bf16) -> hi/lo s8v
__device__ __forceinline__ void unpack8(const u64 w[4], s8v& hi, s8v& lo) {
  #pragma unroll
  for (int j = 0; j < 4; j++) {
    u32 a = (u32)w[j], b = (u32)(w[j] >> 32);
    hi[2*j]   = (short)(u16)a;        lo[2*j]   = (short)(u16)(a >> 16);
    hi[2*j+1] = (short)(u16)b;        lo[2*j+1] = (short)(u16)(b >> 16);
  }
}

// both 16-bit halves of both packed values carry tag in lo-mantissa bits 0-1
__device__ __forceinline__ bool tagok(u64 w, u32 tag) {
  return ((((u32)(w >> 16)) & 3u) == tag) & ((((u32)(w >> 48)) & 3u) == tag);
}
__device__ __forceinline__ int tags8(const u64* w1, const u64* w2, u32 tag) {
  bool ok = true;
  #pragma unroll
  for (int j = 0; j < 4; j++) { ok &= tagok(w1[j], tag); ok &= tagok(w2[j], tag); }
  return __all((int)ok);
}

// 8x dwordx2 speculative sc0 loads (L1-bypass, served by the XCD-shared L2)
// + drain inside the asm (outputs genuinely ready; no rule-18 hazard).
#define POLL8_SC0(W1, W2, P1, P2)                                   \
  asm volatile(                                                     \
    "global_load_dwordx2 %0, %8, off offset:0 sc0\n\t"              \
    "global_load_dwordx2 %1, %8, off offset:8 sc0\n\t"              \
    "global_load_dwordx2 %2, %8, off offset:16 sc0\n\t"             \
    "global_load_dwordx2 %3, %8, off offset:24 sc0\n\t"             \
    "global_load_dwordx2 %4, %9, off offset:0 sc0\n\t"              \
    "global_load_dwordx2 %5, %9, off offset:8 sc0\n\t"              \
    "global_load_dwordx2 %6, %9, off offset:16 sc0\n\t"             \
    "global_load_dwordx2 %7, %9, off offset:24 sc0\n\t"             \
    "s_waitcnt vmcnt(0)"                                            \
    : "=&v"(W1[0]), "=&v"(W1[1]), "=&v"(W1[2]), "=&v"(W1[3]),       \
      "=&v"(W2[0]), "=&v"(W2[1]), "=&v"(W2[2]), "=&v"(W2[3])        \
    : "v"(P1), "v"(P2) : "memory")

// guaranteed-progress agent-scope attempt (exact R4 instruction path)
#define POLL8_AGENT(W1, W2, A1, A2)                                           \
  do {                                                                        \
    _Pragma("unroll")                                                         \
    for (int j_ = 0; j_ < 4; j_++) {                                          \
      W1[j_] = __hip_atomic_load((A1) + j_, __ATOMIC_RELAXED,                 \
                                 __HIP_MEMORY_SCOPE_AGENT);                   \
      W2[j_] = __hip_atomic_load((A2) + j_, __ATOMIC_RELAXED,                 \
                                 __HIP_MEMORY_SCOPE_AGENT);                   \
    }                                                                         \
  } while (0)

// write-through store to the coherence point (agent-store semantics).
__device__ __forceinline__ void store_wt(u32* p, u32 v) {
  asm volatile("global_store_dword %0, %1, off sc0 sc1" :: "v"(p), "v"(v) : "memory");
}

// barrier that waits LDS only (no vmcnt(0) drain of in-flight global stores).
__device__ __forceinline__ void lgkm_barrier() {
  asm volatile("s_waitcnt lgkmcnt(0)" ::: "memory");
  __builtin_amdgcn_sched_barrier(0);
  __builtin_amdgcn_s_barrier();
  __builtin_amdgcn_sched_barrier(0);
  asm volatile("" ::: "memory");
}

__global__ __launch_bounds__(256, 1) void lstm_persist(
    const float* __restrict__ x, const float* __restrict__ Wih,
    const float* __restrict__ Whh, const float* __restrict__ bih,
    const float* __restrict__ bhh, const float* __restrict__ Wout,
    const float* __restrict__ bout, float* __restrict__ out,
    u32* __restrict__ flags, u32* __restrict__ hbuf)
{
  const int bid  = blockIdx.x;
  const int xcd  = bid & 7;
  const int slot = bid >> 3;
  const int ct   = slot & 15;                 // column tile (0..15)
  const int g    = ((slot >> 4) << 3) | xcd;  // batch group (0..15)
  const int tid  = threadIdx.x;
  const int wave = tid >> 6;
  const int lane = tid & 63;
  const int lm   = lane & 15;   // MFMA m (A) / n (B) index
  const int lq   = lane >> 4;   // MFMA quad

  __shared__ u16   Wlds[2][64][392];        // setup W staging; reused for W_out
  __shared__ u16   xlds[2][2][16][136];     // [parity][hi/lo][m][k(128)+pad]
  __shared__ float partial[4][4][16][20];   // [wave][gate][m][hc+pad]

  const int cm  = tid >> 4;
  const int chc = tid & 15;

  const size_t hpar   = (size_t)16 * 16 * 256;  // parity stride (u32 elems)
  const size_t hgbase = (size_t)g * 16 * 256;   // group base within parity

  // ---- XCC handshake: gates ONLY the speculative sc0 poll attempt ----
  u32 xcc;
  asm volatile("s_getreg_b32 %0, hwreg(HW_REG_XCC_ID)" : "=s"(xcc));
  xcc &= 0xFu;
  u32* xccmap = flags;   // 256 u32; poison 0xAAAAAAAA never matches marker
  if (tid == 0)
    __hip_atomic_store(&xccmap[bid], 0xC0DE0000u | xcc,
                       __ATOMIC_RELAXED, __HIP_MEMORY_SCOPE_AGENT);
  int spec;   // 1 = group co-resident on one XCD -> try sc0 fast polls
  {
    int mok = 1;
    if (lane < 16) {
      const int pb = (g >> 3) * 128 + (lane & 15) * 8 + (g & 7);  // peer bid
      u32 v;
      while (true) {
        v = __hip_atomic_load(&xccmap[pb], __ATOMIC_RELAXED, __HIP_MEMORY_SCOPE_AGENT);
        if ((v >> 16) == 0xC0DEu) break;
        __builtin_amdgcn_s_sleep(1);
      }
      mok = ((v & 0xFu) == xcc) ? 1 : 0;
    }
    spec = __all(mok);
  }

  // ---- init this WG's h slice in BOTH parities with unsatisfiable tags.
  // parity0 polls accept tags {2,0} -> init tag 1 (0x00010000).
  // parity1 polls accept tags {1,3} -> init tag 0 (zero).
  // Write-through stores; drained by the first __syncthreads below.
  {
    u32* hz = hbuf + hgbase + (size_t)cm * 256 + ct * 16 + chc;
    store_wt(hz,        0x00010000u);
    store_wt(hz + hpar, 0u);
  }

  // ---- stage W slice (concat Wih rows 0..127, Whh rows 128..383) col-major ----
  for (int it = tid; it < 384 * 64; it += 256) {
    int k = it >> 6;
    int c = it & 63;                              // gate = c>>4, n = c&15
    int gcol = (c >> 4) * 256 + ct * 16 + (c & 15);
    float w = (k < 128) ? Wih[k * 1024 + gcol] : Whh[(k - 128) * 1024 + gcol];
    u16 hi = f2bf(w);
    Wlds[0][c][k] = hi;
    Wlds[1][c][k] = f2bf(w - bf2f(hi));
  }
  __syncthreads();

  // ---- per-wave W fragments in registers: wave owns k-tiles {w, w+4, w+8} ----
  s8v wfrag[3][4][2];
  #pragma unroll
  for (int ki = 0; ki < 3; ki++) {
    const int kt = wave + 4 * ki;
    #pragma unroll
    for (int gg = 0; gg < 4; gg++) {
      #pragma unroll
      for (int p = 0; p < 2; p++)
        wfrag[ki][gg][p] = *(const s8v*)&Wlds[p][gg * 16 + lm][kt * 32 + lq * 8];
    }
  }
  __syncthreads();

  float biasv[4];
  #pragma unroll
  for (int gg = 0; gg < 4; gg++) {
    int col = gg * 256 + ct * 16 + chc;
    biasv[gg] = bih[col] + bhh[col];
  }
  float cstate = 0.0f;

  const int xr  = tid >> 4;
  const int xc0 = (tid & 15) * 8;
  const float* xbase = x + (size_t)(g * 16 + xr) * (T_ * I_) + xc0;

  auto xstore = [&](int par, float4 a, float4 b) {
    float v[8] = {a.x, a.y, a.z, a.w, b.x, b.y, b.z, b.w};
    union { u16 u[8]; s8v s; } hi, lo;
    #pragma unroll
    for (int j = 0; j < 8; j++) {
      u16 h = f2bf(v[j]);
      hi.u[j] = h;
      lo.u[j] = f2bf(v[j] - bf2f(h));
    }
    *(s8v*)&xlds[par][0][xr][xc0] = hi.s;
    *(s8v*)&xlds[par][1][xr][xc0] = lo.s;
  };

  { // x_0 into parity 0
    float4 a = *(const float4*)(xbase + 0);
    float4 b = *(const float4*)(xbase + 4);
    xstore(0, a, b);
  }
  __syncthreads();

  for (int t = 0; t < T_; t++) {
    const int par = t & 1;
    const int pn  = (t + 1) & 1;

    // prefetch x_{t+1} (clamped; read-only data)
    const int tn = (t + 1 < T_) ? (t + 1) : t;
    float4 xa = *(const float4*)(xbase + (size_t)tn * I_);
    float4 xb = *(const float4*)(xbase + (size_t)tn * I_ + 4);

    f4v acc[4];
    #pragma unroll
    for (int gg = 0; gg < 4; gg++)
      #pragma unroll
      for (int r = 0; r < 4; r++) acc[gg][r] = 0.0f;

    // x-part MFMA (k-tile = wave), independent of peers -> runs before poll.
    {
      s8v axh = *(const s8v*)&xlds[par][0][lm][wave * 32 + lq * 8];
      s8v axl = *(const s8v*)&xlds[par][1][lm][wave * 32 + lq * 8];
      #pragma unroll
      for (int gg = 0; gg < 4; gg++) {
        acc[gg] = __builtin_amdgcn_mfma_f32_16x16x32_bf16(axh, wfrag[0][gg][0], acc[gg], 0, 0, 0);
        acc[gg] = __builtin_amdgcn_mfma_f32_16x16x32_bf16(axl, wfrag[0][gg][0], acc[gg], 0, 0, 0);
        acc[gg] = __builtin_amdgcn_mfma_f32_16x16x32_bf16(axh, wfrag[0][gg][1], acc[gg], 0, 0, 0);
      }
    }

    if (t > 0) {
      // Hybrid poll until every word carries tag t&3:
      //   [spec] sc0 attempt (cheap, XCD-L2) -> agent attempt (guaranteed).
      const u32 tag = (u32)(t & 3);
      const u32* hb0 = hbuf + (size_t)par * hpar + hgbase;
      const u32* hp1 = hb0 + (size_t)lm * 256 + (wave * 32 + lq * 8);
      const u32* hp2 = hp1 + 128;
      const u64* a1 = (const u64*)hp1;
      const u64* a2 = (const u64*)hp2;
      u64 w1[4], w2[4];
      while (true) {
        if (spec) {
          POLL8_SC0(w1, w2, hp1, hp2);
          if (tags8(w1, w2, tag)) break;
        }
        POLL8_AGENT(w1, w2, a1, a2);
        if (tags8(w1, w2, tag)) break;
        __builtin_amdgcn_s_sleep(1);
      }
      {
        s8v ahh, ahl;
        unpack8(w1, ahh, ahl);
        #pragma unroll
        for (int gg = 0; gg < 4; gg++) {
          acc[gg] = __builtin_amdgcn_mfma_f32_16x16x32_bf16(ahh, wfrag[1][gg][0], acc[gg], 0, 0, 0);
          acc[gg] = __builtin_amdgcn_mfma_f32_16x16x32_bf16(ahl, wfrag[1][gg][0], acc[gg], 0, 0, 0);
          acc[gg] = __builtin_amdgcn_mfma_f32_16x16x32_bf16(ahh, wfrag[1][gg][1], acc[gg], 0, 0, 0);
        }
        unpack8(w2, ahh, ahl);
        #pragma unroll
        for (int gg = 0; gg < 4; gg++) {
          acc[gg] = __builtin_amdgcn_mfma_f32_16x16x32_bf16(ahh, wfrag[2][gg][0], acc[gg], 0, 0, 0);
          acc[gg] = __builtin_amdgcn_mfma_f32_16x16x32_bf16(ahl, wfrag[2][gg][0], acc[gg], 0, 0, 0);
          acc[gg] = __builtin_amdgcn_mfma_f32_16x16x32_bf16(ahh, wfrag[2][gg][1], acc[gg], 0, 0, 0);
        }
      }
    }

    // write per-wave partial gates (C layout: col=lm, row=lq*4+r)
    #pragma unroll
    for (int gg = 0; gg < 4; gg++)
      #pragma unroll
      for (int r = 0; r < 4; r++)
        partial[wave][gg][lq * 4 + r][lm] = acc[gg][r];

    // convert x_{t+1} into the other parity's LDS planes
    xstore(pn, xa, xb);

    __syncthreads();   // partials + xlds[pn] visible

    // cell update: thread (cm, chc)
    float ga = biasv[0], gb = biasv[1], gc = biasv[2], gd = biasv[3];
    #pragma unroll
    for (int w = 0; w < 4; w++) {
      ga += partial[w][0][cm][chc];
      gb += partial[w][1][cm][chc];
      gc += partial[w][2][cm][chc];
      gd += partial[w][3][cm][chc];
    }
    float i_t = sig_(ga), f_t = sig_(gb), g_t = tanh_(gc), o_t = sig_(gd);
    cstate = f_t * cstate + i_t * g_t;
    float h = o_t * tanh_(cstate);

    // publish h_{t+1}: packed (lo<<16)|hi with tag (t+1)&3. Write-through,
    // fire-and-forget (no drain, no flag).
    u16 hhi = f2bf(h);
    u16 hlo = f2bf(h - bf2f(hhi));
    u32 pk  = ((u32)((hlo & 0xFFFCu) | (u32)((t + 1) & 3)) << 16) | (u32)hhi;
    u32* hw = hbuf + (size_t)pn * hpar + hgbase + (size_t)cm * 256 + ct * 16 + chc;
    store_wt(hw, pk);

    // raw lgkm-only barrier (no vmcnt drain; h store stays in flight)
    lgkm_barrier();
  }

  // ---- output projection: out = h_T @ W_out + b_out ----
  u64 wf0[4], wf1[4];
  {
    const u32* hb0 = hbuf + hgbase;   // h_T lives at parity (1024 & 1) == 0
    const u32* hpa = hb0 + (size_t)lm * 256 + ((wave * 2 + 0) * 32 + lq * 8);
    const u32* hpb = hpa + 32;
    const u64* a1 = (const u64*)hpa;
    const u64* a2 = (const u64*)hpb;
    while (true) {
      if (spec) {
        POLL8_SC0(wf0, wf1, hpa, hpb);
        if (tags8(wf0, wf1, 0u)) break;
      }
      POLL8_AGENT(wf0, wf1, a1, a2);
      if (tags8(wf0, wf1, 0u)) break;
      __builtin_amdgcn_s_sleep(1);
    }
  }
  __syncthreads();
  // stage W_out cols [ct*8, ct*8+8) into Wlds[p][n][k], zero-pad n in [8,16)
  for (int it = tid; it < 16 * 256; it += 256) {
    int n = it >> 8;
    int k = it & 255;
    float w = (n < 8) ? Wout[k * 128 + ct * 8 + n] : 0.0f;
    u16 hi = f2bf(w);
    Wlds[0][n][k] = hi;
    Wlds[1][n][k] = f2bf(w - bf2f(hi));
  }
  __syncthreads();

  f4v oacc;
  #pragma unroll
  for (int r = 0; r < 4; r++) oacc[r] = 0.0f;
  #pragma unroll
  for (int ki = 0; ki < 2; ki++) {
    const int hk = (wave * 2 + ki) * 32 + lq * 8;
    s8v ahh, ahl;
    unpack8(ki == 0 ? wf0 : wf1, ahh, ahl);
    s8v bh  = *(const s8v*)&Wlds[0][lm][hk];
    s8v bl  = *(const s8v*)&Wlds[1][lm][hk];
    oacc = __builtin_amdgcn_mfma_f32_16x16x32_bf16(ahh, bh, oacc, 0, 0, 0);
    oacc = __builtin_amdgcn_mfma_f32_16x16x32_bf16(ahl, bh, oacc, 0, 0, 0);
    oacc = __builtin_amdgcn_mfma_f32_16x16x32_bf16(ahh, bl, oacc, 0, 0, 0);
  }
  #pragma unroll
  for (int r = 0; r < 4; r++) partial[wave][0][lq * 4 + r][lm] = oacc[r];
  __syncthreads();

  if (tid < 128) {
    int m  = tid >> 3;
    int oc = tid & 7;
    float v = bout[ct * 8 + oc];
    #pragma unroll
    for (int w = 0; w < 4; w++) v += partial[w][0][m][oc];
    out[(size_t)(g * 16 + m) * 128 + ct * 8 + oc] = v;
  }
}

extern "C" void kernel_launch(void* const* d_in, const int* in_sizes, int n_in,
                              void* d_out, int out_size, void* d_ws, size_t ws_size,
                              hipStream_t stream) {
  const float* x    = (const float*)d_in[0];
  const float* Wih  = (const float*)d_in[1];
  const float* Whh  = (const float*)d_in[2];
  const float* bih  = (const float*)d_in[3];
  const float* bhh  = (const float*)d_in[4];
  const float* Wout = (const float*)d_in[5];
  const float* bout = (const float*)d_in[6];
  float* out = (float*)d_out;

  char* ws = (char*)d_ws;
  u32* flags = (u32*)ws;               // xccmap: 256 u32 (poison-safe markers)
  u32* hbuf  = (u32*)(ws + 4096);      // 2 parities * 16 g * 16 * 256 * 4 B = 512 KB
  hipLaunchKernelGGL(lstm_persist, dim3(256), dim3(256), 0, stream,
                     x, Wih, Whh, bih, bhh, Wout, bout, out, flags, hbuf);
}